// Round 1
// baseline (1539.982 us; speedup 1.0000x reference)
//
#include <hip/hip_runtime.h>
#include <math.h>

// Fused WaveNet-ish encoder for MI355X.
// One block per batch element; h[256][128] resident in LDS across all stages.
// fp32 vector-ALU implementation (no fp32 MFMA on CDNA4).

#define BATCH  256
#define INCH   1024
#define HID    256
#define TLEN   128
#define CTXN   16
#define NLAY   8
#define LEAKF  0.2f
#define EPSF   1e-8f

// LDS layout (floats):
//   hsh  : HID*TLEN      = 32768
//   scr  : 32*TLEN       = 4096   (per-o-group sumsq partials)
//   invn : TLEN          = 128
//   attn : TLEN          = 128
//   redf : 32                     (best value + best index)
#define LDS_FLOATS (HID * TLEN + 32 * TLEN + TLEN + TLEN + 32)

__global__ __launch_bounds__(1024, 4)
void wavenet_fused(const float* __restrict__ x,
                   const float* __restrict__ proj_w,
                   const float* __restrict__ proj_b,
                   const float* __restrict__ conv_w,
                   const float* __restrict__ conv_b,
                   const float* __restrict__ ev_w,
                   const float* __restrict__ ev_b,
                   const float* __restrict__ sw_w,
                   const float* __restrict__ sw_b,
                   float* __restrict__ out)
{
    extern __shared__ float lds[];
    float* hsh  = lds;                       // [HID][TLEN]
    float* scr  = hsh + HID * TLEN;          // [32][TLEN]
    float* invn = scr + 32 * TLEN;           // [TLEN]
    float* attn = invn + TLEN;               // [TLEN]
    float* redf = attn + TLEN;               // [32]

    const int b   = blockIdx.x;
    const int tid = threadIdx.x;
    const int og  = tid >> 5;    // 0..31  (8 output channels each)
    const int tg  = tid & 31;    // 0..31  (4 time steps each)
    const int t0  = tg << 2;
    const int o0  = og << 3;

    float acc[8][4];

    // ---------------- 1x1 projection: h = proj_w @ x + proj_b ----------------
    {
        #pragma unroll
        for (int j = 0; j < 8; ++j) {
            const float pb = proj_b[o0 + j];
            #pragma unroll
            for (int t = 0; t < 4; ++t) acc[j][t] = pb;
        }
        const float* xb = x + (size_t)b * INCH * TLEN;
        for (int i = 0; i < INCH; i += 4) {
            float xr[4][4];
            #pragma unroll
            for (int q = 0; q < 4; ++q) {
                const float4 v = *(const float4*)(xb + (i + q) * TLEN + t0);
                xr[q][0] = v.x; xr[q][1] = v.y; xr[q][2] = v.z; xr[q][3] = v.w;
            }
            #pragma unroll
            for (int j = 0; j < 8; ++j) {
                const float4 w = *(const float4*)(proj_w + (o0 + j) * INCH + i);
                const float wv[4] = {w.x, w.y, w.z, w.w};
                #pragma unroll
                for (int q = 0; q < 4; ++q) {
                    #pragma unroll
                    for (int t = 0; t < 4; ++t)
                        acc[j][t] = fmaf(wv[q], xr[q][t], acc[j][t]);
                }
            }
        }
        #pragma unroll
        for (int j = 0; j < 8; ++j) {
            float4 v = {acc[j][0], acc[j][1], acc[j][2], acc[j][3]};
            *(float4*)(hsh + (o0 + j) * TLEN + t0) = v;
        }
    }
    __syncthreads();

    // ---------------- 8 dilated residual layers ----------------
    const int DIL[NLAY] = {1, 2, 4, 8, 16, 32, 64, 1};
    #pragma unroll 1
    for (int l = 0; l < NLAY; ++l) {
        const int d = DIL[l];
        #pragma unroll
        for (int j = 0; j < 8; ++j) {
            const float cb = conv_b[l * HID + o0 + j];
            #pragma unroll
            for (int t = 0; t < 4; ++t) acc[j][t] = cb;
        }
        const float* cw = conv_w + (size_t)l * HID * HID * 2;
        for (int i = 0; i < HID; i += 2) {
            const float* hr0 = hsh + i * TLEN;
            const float* hr1 = hr0 + TLEN;
            float a0[4], a1[4], s0[4], s1[4];
            {
                const float4 v0 = *(const float4*)(hr0 + t0);
                a0[0] = v0.x; a0[1] = v0.y; a0[2] = v0.z; a0[3] = v0.w;
                const float4 v1 = *(const float4*)(hr1 + t0);
                a1[0] = v1.x; a1[1] = v1.y; a1[2] = v1.z; a1[3] = v1.w;
            }
            #pragma unroll
            for (int t = 0; t < 4; ++t) {
                const int ts = t0 + t + d;           // anti-causal tap (future)
                const int tc = ts < TLEN ? ts : TLEN - 1;
                const float u0 = hr0[tc];
                const float u1 = hr1[tc];
                s0[t] = ts < TLEN ? u0 : 0.f;        // right zero-pad
                s1[t] = ts < TLEN ? u1 : 0.f;
            }
            #pragma unroll
            for (int j = 0; j < 8; ++j) {
                // w = [w(o,i,0), w(o,i,1), w(o,i+1,0), w(o,i+1,1)]
                const float4 w = *(const float4*)(cw + (o0 + j) * (HID * 2) + i * 2);
                #pragma unroll
                for (int t = 0; t < 4; ++t) {
                    float a = fmaf(w.x, a0[t], acc[j][t]);
                    a = fmaf(w.y, s0[t], a);
                    a = fmaf(w.z, a1[t], a);
                    acc[j][t] = fmaf(w.w, s1[t], a);
                }
            }
        }
        // leaky relu + residual skip + per-t partial sum of squares
        float ps[4] = {0.f, 0.f, 0.f, 0.f};
        #pragma unroll
        for (int j = 0; j < 8; ++j) {
            #pragma unroll
            for (int t = 0; t < 4; ++t) {
                float y = acc[j][t];
                y = y > 0.f ? y : LEAKF * y;
                const float v = y + hsh[(o0 + j) * TLEN + t0 + t]; // own values
                acc[j][t] = v;
                ps[t] = fmaf(v, v, ps[t]);
            }
        }
        #pragma unroll
        for (int t = 0; t < 4; ++t) scr[og * TLEN + t0 + t] = ps[t];
        __syncthreads();   // all h reads + scr writes complete
        if (tid < TLEN) {
            float s = 0.f;
            #pragma unroll
            for (int g = 0; g < 32; ++g) s += scr[g * TLEN + tid];
            invn[tid] = 1.f / (sqrtf(s) + EPSF);
        }
        __syncthreads();
        {
            const float iv[4] = {invn[t0], invn[t0 + 1], invn[t0 + 2], invn[t0 + 3]};
            #pragma unroll
            for (int j = 0; j < 8; ++j) {
                float4 v = {acc[j][0] * iv[0], acc[j][1] * iv[1],
                            acc[j][2] * iv[2], acc[j][3] * iv[3]};
                *(float4*)(hsh + (o0 + j) * TLEN + t0) = v;
            }
        }
        __syncthreads();
    }

    // ---------------- head: switch conv -> relu -> top-1 ----------------
    if (tid < TLEN) {
        float s = sw_b[0];
        for (int o = 0; o < HID; ++o) s = fmaf(sw_w[o], hsh[o * TLEN + tid], s);
        attn[tid] = s > 0.f ? s : 0.f;
    }
    __syncthreads();
    if (tid == 0) {
        float best = attn[0];
        int bi = 0;
        for (int t = 1; t < TLEN; ++t) {
            if (attn[t] > best) { best = attn[t]; bi = t; }  // first-max, jax tie semantics
        }
        redf[0] = best;
        ((int*)redf)[1] = bi;
    }
    __syncthreads();
    const float bestv = redf[0];
    const int   bidx  = ((const int*)redf)[1];

    // event vectors at the selected time step: out[b, 0, ctx]
    if (tid < CTXN) {
        float s = ev_b[tid];
        const float* ew = ev_w + tid * HID;
        for (int o = 0; o < HID; ++o) s = fmaf(ew[o], hsh[o * TLEN + bidx], s);
        out[b * CTXN + tid] = s;
    }
    // scheduling one-hot: out[BATCH*CTXN + b*TLEN + t]
    if (tid >= 256 && tid < 256 + TLEN) {
        const int t = tid - 256;
        out[BATCH * CTXN + b * TLEN + t] = (t == bidx) ? bestv : 0.f;
    }
}

extern "C" void kernel_launch(void* const* d_in, const int* in_sizes, int n_in,
                              void* d_out, int out_size, void* d_ws, size_t ws_size,
                              hipStream_t stream) {
    const float* x      = (const float*)d_in[0];
    const float* proj_w = (const float*)d_in[1];
    const float* proj_b = (const float*)d_in[2];
    const float* conv_w = (const float*)d_in[3];
    const float* conv_b = (const float*)d_in[4];
    const float* ev_w   = (const float*)d_in[5];
    const float* ev_b   = (const float*)d_in[6];
    const float* sw_w   = (const float*)d_in[7];
    const float* sw_b   = (const float*)d_in[8];
    float* out = (float*)d_out;

    const size_t smem = (size_t)LDS_FLOATS * sizeof(float);  // ~145 KiB, gfx950 allows 160 KiB
    (void)hipFuncSetAttribute((const void*)wavenet_fused,
                              hipFuncAttributeMaxDynamicSharedMemorySize, (int)smem);
    wavenet_fused<<<BATCH, 1024, smem, stream>>>(x, proj_w, proj_b, conv_w, conv_b,
                                                 ev_w, ev_b, sw_w, sw_b, out);
}